// Round 11
// baseline (435.062 us; speedup 1.0000x reference)
//
#include <hip/hip_runtime.h>
#include <math.h>

typedef unsigned short u16;
typedef unsigned int u32;
typedef float f32x4 __attribute__((ext_vector_type(4)));
typedef unsigned short u16x8 __attribute__((ext_vector_type(8)));
typedef unsigned short u16x4 __attribute__((ext_vector_type(4)));
typedef _Float16 f16x8 __attribute__((ext_vector_type(8)));
typedef _Float16 f16x4 __attribute__((ext_vector_type(4)));

#define DEV static __device__ __forceinline__

constexpr int BB = 16, NN = 512, DIM = 512, DEP = 2;
constexpr long ROWS = (long)BB * NN;  // 8192

DEV u16 f2h(float f){ _Float16 h = (_Float16)f; return __builtin_bit_cast(u16, h); }
DEV float h2f(u16 u){ return (float)__builtin_bit_cast(_Float16, u); }
DEV f32x4 mfma16h(u16x8 a, u16x8 b, f32x4 c){
  return __builtin_amdgcn_mfma_f32_16x16x32_f16(__builtin_bit_cast(f16x8, a), __builtin_bit_cast(f16x8, b), c, 0, 0, 0);
}
DEV u32 pkrtz(float a, float b){ auto r = __builtin_amdgcn_cvt_pkrtz(a, b); return __builtin_bit_cast(u32, r); }
DEV u16x4 cvt4(f32x4 a){ f16x4 h = {(_Float16)a[0], (_Float16)a[1], (_Float16)a[2], (_Float16)a[3]}; return __builtin_bit_cast(u16x4, h); }
DEV float gelu_f(float x){ return 0.5f * x * (1.f + tanhf(0.79788456080286536f * (x + 0.044715f * x * x * x))); }

// async global->LDS, 16B per lane. LDS dest is wave-uniform base + lane*16 (m104).
DEV void gload16(const u16* g, u16* l){
  __builtin_amdgcn_global_load_lds((const __attribute__((address_space(1))) unsigned int*)(const void*)g,
                                   (__attribute__((address_space(3))) unsigned int*)(void*)l, 16, 0, 0);
}

DEV f32x4 vaddv(f32x4 a, f32x4 b){ f32x4 r; r[0]=a[0]+b[0]; r[1]=a[1]+b[1]; r[2]=a[2]+b[2]; r[3]=a[3]+b[3]; return r; }
DEV f32x4 shfl4(f32x4 v, int m){ f32x4 r; r[0]=__shfl_xor(v[0],m); r[1]=__shfl_xor(v[1],m); r[2]=__shfl_xor(v[2],m); r[3]=__shfl_xor(v[3],m); return r; }

// ---------------- all expert weight transpose-casts (f32 -> f16, [K][N] -> [N][K]) ----------------
__global__ __launch_bounds__(256) void castAll(const float* __restrict__ qkv_w, const float* __restrict__ ao_w,
                                               const float* __restrict__ mlp_w1, const float* __restrict__ mlp_w2,
                                               u16* __restrict__ WQ, u16* __restrict__ WAO,
                                               u16* __restrict__ W1t, u16* __restrict__ W2t)
{
  const int z = blockIdx.z;
  const float* src; u16* dst; int Nd;
  if (z < 8){ src = qkv_w + (long)z * 512 * 1536; dst = WQ + (long)z * 512 * 1536; Nd = 1536; }
  else {
    int m = (z - 8) >> 3, zz = (z - 8) & 7;
    src = (m == 0 ? ao_w : m == 1 ? mlp_w1 : mlp_w2) + (long)zz * 512 * 512;
    dst = (m == 0 ? WAO : m == 1 ? W1t : W2t) + (long)zz * 512 * 512;
    Nd = 512;
  }
  const int n0 = blockIdx.y * 32;
  if (n0 >= Nd) return;
  const int k0 = blockIdx.x * 32;
  __shared__ float t[32][33];
  const int r = threadIdx.x >> 5, cc = threadIdx.x & 31;
  #pragma unroll
  for (int i = 0; i < 4; i++) t[r + i * 8][cc] = src[(long)(k0 + r + i * 8) * Nd + n0 + cc];
  __syncthreads();
  #pragma unroll
  for (int i = 0; i < 4; i++) dst[(long)(n0 + r + i * 8) * 512 + k0 + cc] = f2h(t[cc][r + i * 8]);
}

// ---------------- proj weight: [2048][512] f32 -> [512][2048] f16 ----------------
__global__ __launch_bounds__(256) void castTp(const float* __restrict__ src, u16* __restrict__ dst)
{
  __shared__ float t[32][33];
  const int k0 = blockIdx.x * 32, n0 = blockIdx.y * 32;
  const int r = threadIdx.x >> 5, cc = threadIdx.x & 31;
  #pragma unroll
  for (int i = 0; i < 4; i++) t[r + i * 8][cc] = src[(long)(k0 + r + i * 8) * 512 + n0 + cc];
  __syncthreads();
  #pragma unroll
  for (int i = 0; i < 4; i++) dst[(long)(n0 + r + i * 8) * 2048 + k0 + cc] = f2h(t[cc][r + i * 8]);
}

// ---------------- X f32 -> f16 ----------------
__global__ __launch_bounds__(256) void xcast(const float* __restrict__ X, u16* __restrict__ Xf)
{
  long i0 = ((long)blockIdx.x * 256 + threadIdx.x) * 8;
  f32x4 v0 = *(const f32x4*)(X + i0), v1 = *(const f32x4*)(X + i0 + 4);
  u16x8 hh;
  hh[0] = f2h(v0[0]); hh[1] = f2h(v0[1]); hh[2] = f2h(v0[2]); hh[3] = f2h(v0[3]);
  hh[4] = f2h(v1[0]); hh[5] = f2h(v1[1]); hh[6] = f2h(v1[2]); hh[7] = f2h(v1[3]);
  *(u16x8*)(Xf + i0) = hh;
}

// ---------------- proj GEMM: H[8192,512] = Xf @ WP^T + bias, f16 out, swapped-operand epilogue ----------------
__global__ __launch_bounds__(256) void gemm_proj(const u16* __restrict__ Xf, const u16* __restrict__ WP,
                                                 const float* __restrict__ bias, u16* __restrict__ Hout)
{
  const int mt = blockIdx.x, nt = blockIdx.y;
  __shared__ __align__(16) u16 As[64 * 64], Bs[128 * 64];
  const int tid = threadIdx.x, lane = tid & 63, wv = tid >> 6;
  const int wm = wv >> 1, wn = wv & 1, l4 = lane >> 4, l15 = lane & 15;
  const long a0 = (long)(mt * 64) * 2048, b0 = (long)(nt * 128) * 2048;
  const int srow = tid >> 3, sslot = tid & 7;
  f32x4 zero = {0.f, 0.f, 0.f, 0.f};
  f32x4 acc[2][4];
  #pragma unroll
  for (int mi = 0; mi < 2; mi++)
    #pragma unroll
    for (int ni = 0; ni < 4; ni++) acc[mi][ni] = zero;

  for (int kt = 0; kt < 2048; kt += 64){
    #pragma unroll
    for (int p = 0; p < 2; p++){
      int r = p * 32 + srow;
      int sg = sslot ^ (r & 7);
      gload16(Xf + a0 + (long)r * 2048 + kt + sg * 8, As + p * 2048 + wv * 512);
    }
    #pragma unroll
    for (int p = 0; p < 4; p++){
      int r = p * 32 + srow;
      int sg = sslot ^ (r & 7);
      gload16(WP + b0 + (long)r * 2048 + kt + sg * 8, Bs + p * 2048 + wv * 512);
    }
    __syncthreads();
    #pragma unroll
    for (int ks = 0; ks < 2; ks++){
      u16x8 af[2], bfr[4];
      #pragma unroll
      for (int mi = 0; mi < 2; mi++){
        int ra = wm * 32 + mi * 16 + l15;
        af[mi] = *(const u16x8*)(As + ra * 64 + ((((ks << 2) | l4)) ^ (ra & 7)) * 8);
      }
      #pragma unroll
      for (int ni = 0; ni < 4; ni++){
        int rb = wn * 64 + ni * 16 + l15;
        bfr[ni] = *(const u16x8*)(Bs + rb * 64 + ((((ks << 2) | l4)) ^ (rb & 7)) * 8);
      }
      #pragma unroll
      for (int mi = 0; mi < 2; mi++)
        #pragma unroll
        for (int ni = 0; ni < 4; ni++)
          acc[mi][ni] = mfma16h(bfr[ni], af[mi], acc[mi][ni]);
    }
    __syncthreads();
  }
  // swapped: acc rows = N cols (l4*4+i), acc cols = M row (l15)
  #pragma unroll
  for (int mi = 0; mi < 2; mi++)
    #pragma unroll
    for (int ni = 0; ni < 4; ni++){
      const int grow = mt * 64 + wm * 32 + mi * 16 + l15;
      const int gc0 = nt * 128 + wn * 64 + ni * 16 + l4 * 4;
      f32x4 bb = *(const f32x4*)(bias + gc0);
      f32x4 a = vaddv(acc[mi][ni], bb);
      *(u16x4*)(Hout + (long)grow * 512 + gc0) = cvt4(a);
    }
}

// ---------------- generic f16 GEMM over compacted (e,b) pairs, swapped-operand epilogue ----------------
// MT = M-tile rows (128 or 64). grid.x = 32 * (512/MT), grid.y = N/128.
// EPI: 0 = f16 out (+bias), 1 = f16 gelu out, 2 = f16 residual RMW, 3 = f16 out = resin + acc + bias
template<int EPI, int MT>
__global__ __launch_bounds__(256) void gemm_bt(const u16* __restrict__ A, int K, long sAe,
                                               const u16* __restrict__ Bt, long sBe,
                                               const float* __restrict__ bias, int sBiasE,
                                               u16* __restrict__ Cout, long sCe, int N,
                                               const int* __restrict__ pairs,
                                               const u16* __restrict__ resin)
{
  constexpr int MI = MT / 32;          // a-frags per wave == staging iterations
  constexpr int PSH = (MT == 128) ? 2 : 3;
  const int pe = pairs[blockIdx.x >> PSH];
  const int e = pe >> 4, bb = pe & 15;
  const int row0 = bb * 512 + (blockIdx.x & ((1 << PSH) - 1)) * MT;
  const int nt = blockIdx.y;
  A += (long)e * sAe + (long)row0 * K;
  Bt += (long)e * sBe + (long)(nt * 128) * K;
  const float* bias_e = bias ? bias + (long)e * sBiasE : nullptr;

  __shared__ __align__(16) u16 As[MT * 64];
  __shared__ __align__(16) u16 Bs[128 * 64];
  const int tid = threadIdx.x, lane = tid & 63, wv = tid >> 6;
  const int wm = wv >> 1, wn = wv & 1, l4 = lane >> 4, l15 = lane & 15;
  const int srow = tid >> 3, sslot = tid & 7;
  f32x4 zero = {0.f, 0.f, 0.f, 0.f};
  f32x4 acc[MI][4];
  #pragma unroll
  for (int mi = 0; mi < MI; mi++)
    #pragma unroll
    for (int ni = 0; ni < 4; ni++) acc[mi][ni] = zero;

  for (int kt = 0; kt < K; kt += 64){
    #pragma unroll
    for (int p = 0; p < MI; p++){
      int r = p * 32 + srow;
      int sg = sslot ^ (r & 7);
      gload16(A + (long)r * K + kt + sg * 8, As + p * 2048 + wv * 512);
    }
    #pragma unroll
    for (int p = 0; p < 4; p++){
      int r = p * 32 + srow;
      int sg = sslot ^ (r & 7);
      gload16(Bt + (long)r * K + kt + sg * 8, Bs + p * 2048 + wv * 512);
    }
    __syncthreads();
    #pragma unroll
    for (int ks = 0; ks < 2; ks++){
      u16x8 af[MI], bfr[4];
      #pragma unroll
      for (int mi = 0; mi < MI; mi++){
        int ra = wm * (MT / 2) + mi * 16 + l15;
        af[mi] = *(const u16x8*)(As + ra * 64 + ((((ks << 2) | l4)) ^ (ra & 7)) * 8);
      }
      #pragma unroll
      for (int ni = 0; ni < 4; ni++){
        int rb = wn * 64 + ni * 16 + l15;
        bfr[ni] = *(const u16x8*)(Bs + rb * 64 + ((((ks << 2) | l4)) ^ (rb & 7)) * 8);
      }
      #pragma unroll
      for (int mi = 0; mi < MI; mi++)
        #pragma unroll
        for (int ni = 0; ni < 4; ni++)
          acc[mi][ni] = mfma16h(bfr[ni], af[mi], acc[mi][ni]);
    }
    __syncthreads();
  }

  // swapped layout: per (mi,ni) thread owns 4 consecutive cols at one row
  #pragma unroll
  for (int mi = 0; mi < MI; mi++)
    #pragma unroll
    for (int ni = 0; ni < 4; ni++){
      const int grow = row0 + wm * (MT / 2) + mi * 16 + l15;
      const int gc0 = nt * 128 + wn * 64 + ni * 16 + l4 * 4;
      f32x4 a = acc[mi][ni];
      if (bias_e){
        f32x4 bb2 = *(const f32x4*)(bias_e + gc0);
        a = vaddv(a, bb2);
      }
      long idx = (long)e * sCe + (long)grow * N + gc0;
      if (EPI == 0){
        *(u16x4*)(Cout + idx) = cvt4(a);
      } else if (EPI == 1){
        f32x4 gg;
        #pragma unroll
        for (int i = 0; i < 4; i++) gg[i] = gelu_f(a[i]);
        *(u16x4*)(Cout + idx) = cvt4(gg);
      } else if (EPI == 2){
        u16x4 old = *(const u16x4*)(Cout + idx);
        f32x4 r;
        #pragma unroll
        for (int i = 0; i < 4; i++) r[i] = h2f(old[i]) + a[i];
        *(u16x4*)(Cout + idx) = cvt4(r);
      } else {
        u16x4 old = *(const u16x4*)(resin + (long)grow * N + gc0);
        f32x4 r;
        #pragma unroll
        for (int i = 0; i < 4; i++) r[i] = h2f(old[i]) + a[i];
        *(u16x4*)(Cout + idx) = cvt4(r);
      }
    }
}

// ---------------- flash attention, swapped-QK + swapped-PV, f16, compacted pairs ----------------
// grid = 1024, XCD-friendly order: p = bx&31, hh = (bx>>5)&7, qt = bx>>8.
__global__ __launch_bounds__(256) void attn(const u16* __restrict__ qkv, u16* __restrict__ obf, const int* __restrict__ pairs)
{
  const int pe = pairs[blockIdx.x & 31];
  const int e = pe >> 4, b = pe & 15;
  const int hh = (blockIdx.x >> 5) & 7;
  const int qt = blockIdx.x >> 8;
  const u16* base = qkv + ((long)e * ROWS + (long)b * NN) * 1536;

  __shared__ u16 Ks[64 * 72];
  __shared__ u16 Vts[64 * 72];
  __shared__ u16 Ps[4][32 * 72];
  const int tid = threadIdx.x, lane = tid & 63, wv = tid >> 6;
  const int l4 = lane >> 4, l15 = lane & 15;
  const int qr0 = qt * 128 + wv * 32;
  constexpr float CSC = 0.125f * 1.44269504088896340736f;

  u16x8 qf[2][2];
  #pragma unroll
  for (int mi = 0; mi < 2; mi++)
    #pragma unroll
    for (int ks = 0; ks < 2; ks++){
      u16x8 raw = *(const u16x8*)(base + (long)(qr0 + mi * 16 + l15) * 1536 + hh * 64 + ks * 32 + l4 * 8);
      #pragma unroll
      for (int j = 0; j < 8; j++) qf[mi][ks][j] = f2h(h2f(raw[j]) * CSC);
    }

  f32x4 zero = {0.f, 0.f, 0.f, 0.f};
  f32x4 o[2][4]; float lrun[2] = {0.f, 0.f};
  #pragma unroll
  for (int mi = 0; mi < 2; mi++)
    #pragma unroll
    for (int df = 0; df < 4; df++) o[mi][df] = zero;
  const int sr = tid >> 3, ss = tid & 7;

  for (int c = 0; c < 8; c++){
    const int kk0 = c * 64;
    u16x8 kv0 = *(const u16x8*)(base + (long)(kk0 + sr) * 1536 + 512 + hh * 64 + ss * 8);
    u16x8 kv1 = *(const u16x8*)(base + (long)(kk0 + sr + 32) * 1536 + 512 + hh * 64 + ss * 8);
    u16x8 vv0 = *(const u16x8*)(base + (long)(kk0 + sr) * 1536 + 1024 + hh * 64 + ss * 8);
    u16x8 vv1 = *(const u16x8*)(base + (long)(kk0 + sr + 32) * 1536 + 1024 + hh * 64 + ss * 8);
    __syncthreads();
    *(u16x8*)(Ks + sr * 72 + ss * 8) = kv0;
    *(u16x8*)(Ks + (sr + 32) * 72 + ss * 8) = kv1;
    #pragma unroll
    for (int j = 0; j < 8; j++){
      int d = ss * 8 + j;
      Vts[d * 72 + (sr ^ (ss * 8))] = vv0[j];
      Vts[d * 72 + ((sr + 32) ^ (ss * 8))] = vv1[j];
    }
    __syncthreads();

    u16x8 kf[4][2];
    #pragma unroll
    for (int n = 0; n < 4; n++)
      #pragma unroll
      for (int ks = 0; ks < 2; ks++)
        kf[n][ks] = *(const u16x8*)(Ks + (n * 16 + l15) * 72 + ks * 32 + l4 * 8);

    f32x4 sv[2][4];
    __builtin_amdgcn_s_setprio(1);
    #pragma unroll
    for (int mi = 0; mi < 2; mi++)
      #pragma unroll
      for (int n = 0; n < 4; n++){
        sv[mi][n] = zero;
        sv[mi][n] = mfma16h(kf[n][0], qf[mi][0], sv[mi][n]);
        sv[mi][n] = mfma16h(kf[n][1], qf[mi][1], sv[mi][n]);
      }
    __builtin_amdgcn_s_setprio(0);

    #pragma unroll
    for (int mi = 0; mi < 2; mi++){
      float lp = 0.f;
      #pragma unroll
      for (int n = 0; n < 4; n++){
        float p0 = __builtin_amdgcn_exp2f(sv[mi][n][0]);
        float p1 = __builtin_amdgcn_exp2f(sv[mi][n][1]);
        float p2 = __builtin_amdgcn_exp2f(sv[mi][n][2]);
        float p3 = __builtin_amdgcn_exp2f(sv[mi][n][3]);
        lp += (p0 + p1) + (p2 + p3);
        union { u32 w[2]; u16x4 h; } pk;
        pk.w[0] = pkrtz(p0, p1);
        pk.w[1] = pkrtz(p2, p3);
        *(u16x4*)(&Ps[wv][(mi * 16 + l15) * 72 + n * 16 + l4 * 4]) = pk.h;
      }
      lp += __shfl_xor(lp, 16);
      lp += __shfl_xor(lp, 32);
      lrun[mi] += lp;
    }

    u16x8 pf[2][2], vf[4][2];
    #pragma unroll
    for (int mi = 0; mi < 2; mi++)
      #pragma unroll
      for (int k2 = 0; k2 < 2; k2++)
        pf[mi][k2] = *(const u16x8*)(&Ps[wv][(mi * 16 + l15) * 72 + k2 * 32 + l4 * 8]);
    #pragma unroll
    for (int df = 0; df < 4; df++)
      #pragma unroll
      for (int k2 = 0; k2 < 2; k2++){
        int d = df * 16 + l15;
        int swz = ((d >> 3) & 7) * 8;
        vf[df][k2] = *(const u16x8*)(Vts + d * 72 + ((k2 * 32 + l4 * 8) ^ swz));
      }
    // swapped PV: o rows = d (l4*4+i), cols = q (l15)
    __builtin_amdgcn_s_setprio(1);
    #pragma unroll
    for (int mi = 0; mi < 2; mi++)
      #pragma unroll
      for (int df = 0; df < 4; df++){
        o[mi][df] = mfma16h(vf[df][0], pf[mi][0], o[mi][df]);
        o[mi][df] = mfma16h(vf[df][1], pf[mi][1], o[mi][df]);
      }
    __builtin_amdgcn_s_setprio(0);
  }

  // q = qr0 + mi*16 + l15 matches lrun[mi]'s lane -> no LDS roundtrip
  #pragma unroll
  for (int mi = 0; mi < 2; mi++){
    float inv = 1.f / lrun[mi];
    long rb = (long)e * ROWS * DIM + (long)(b * NN + qr0 + mi * 16 + l15) * DIM + hh * 64;
    #pragma unroll
    for (int df = 0; df < 4; df++){
      f32x4 a;
      #pragma unroll
      for (int i = 0; i < 4; i++) a[i] = o[mi][df][i] * inv;
      *(u16x4*)(obf + rb + df * 16 + l4 * 4) = cvt4(a);
    }
  }
}

// ---------------- LayerNorm rows (f16 in, f16 out), one wave per row, vectorized: grid = 4096 ----------------
__global__ __launch_bounds__(256) void ln_rows(const u16* __restrict__ hin, long sHe,
                                               const float* __restrict__ g, const float* __restrict__ bta,
                                               int sGE, u16* __restrict__ outb, const int* __restrict__ pairs)
{
  const int pe = pairs[blockIdx.x >> 7];
  const int e = pe >> 4;
  const int tid = threadIdx.x, lane = tid & 63, wv = tid >> 6;
  const int row = (pe & 15) * 512 + ((blockIdx.x & 127) << 2) + wv;
  const u16* x = hin + (long)e * sHe + (long)row * DIM + lane * 8;
  u16x8 vh = *(const u16x8*)x;
  float v[8];
  #pragma unroll
  for (int j = 0; j < 8; j++) v[j] = h2f(vh[j]);
  float s = 0.f, sq = 0.f;
  #pragma unroll
  for (int j = 0; j < 8; j++){ s += v[j]; sq += v[j] * v[j]; }
  #pragma unroll
  for (int m = 32; m >= 1; m >>= 1){ s += __shfl_xor(s, m); sq += __shfl_xor(sq, m); }
  float mean = s * (1.f / DIM); float var = sq * (1.f / DIM) - mean * mean;
  float inv = rsqrtf(var + 1e-5f);
  const float* ge = g + (long)e * sGE + lane * 8;
  const float* be = bta + (long)e * sGE + lane * 8;
  f32x4 g0 = *(const f32x4*)ge, g1 = *(const f32x4*)(ge + 4);
  f32x4 b0 = *(const f32x4*)be, b1 = *(const f32x4*)(be + 4);
  u16x8 yo;
  #pragma unroll
  for (int j = 0; j < 4; j++) yo[j] = f2h((v[j] - mean) * inv * g0[j] + b0[j]);
  #pragma unroll
  for (int j = 0; j < 4; j++) yo[4 + j] = f2h((v[4 + j] - mean) * inv * g1[j] + b1[j]);
  *(u16x8*)(outb + ((long)e * ROWS + row) * DIM + lane * 8) = yo;
}

// ---------------- bag stage 1: partial means. grid (16 b, 8 c), 512 thr ----------------
__global__ __launch_bounds__(512) void bag_partial(const u16* __restrict__ H, float* __restrict__ bagp)
{
  const int b = blockIdx.x, c = blockIdx.y;
  const int tid = threadIdx.x;
  const u16* r = H + ((long)b * 512 + c * 64) * DIM + tid;
  float s = 0.f;
  #pragma unroll 8
  for (int n = 0; n < 64; n++) s += h2f(r[n * DIM]);
  bagp[((long)c * BB + b) * DIM + tid] = s;
}

// ---------------- router stage 2: partial layer-1. grid (8 kc, 16 b), 256 thr ----------------
__global__ __launch_bounds__(256) void router_mm(const float* __restrict__ bagp, const float* __restrict__ rw1,
                                                 float* __restrict__ hidp)
{
  const int kc = blockIdx.x, b = blockIdx.y;
  const int tid = threadIdx.x;
  __shared__ float bs[64];
  if (tid < 64){
    int k = kc * 64 + tid;
    float s = 0.f;
    #pragma unroll
    for (int c = 0; c < 8; c++) s += bagp[((long)c * BB + b) * DIM + k];
    bs[tid] = s * (1.f / NN);
  }
  __syncthreads();
  float a = 0.f;
  #pragma unroll 8
  for (int k = 0; k < 64; k++) a += bs[k] * rw1[(long)(kc * 64 + k) * 256 + tid];
  hidp[((long)b * 8 + kc) * 256 + tid] = a;
}

// ---------------- router stage 3: reduce + relu + layer2 + softmax + top2 + PAIRS. 16 blocks, 256 thr ----------------
__global__ __launch_bounds__(256) void router_fin(const float* __restrict__ hidp,
                                                  const float* __restrict__ rb1,
                                                  const float* __restrict__ rw2, const float* __restrict__ rb2,
                                                  float* __restrict__ gout, float* __restrict__ wexp, int* __restrict__ pairs)
{
  const int b = blockIdx.x;
  const int tid = threadIdx.x, lane = tid & 63, wv = tid >> 6;
  __shared__ f32x4 red2[4];
  float a = rb1[tid];
  #pragma unroll
  for (int kc = 0; kc < 8; kc++) a += hidp[((long)b * 8 + kc) * 256 + tid];
  float h = fmaxf(a, 0.f);
  f32x4 w4 = *(const f32x4*)(rw2 + tid * 4);
  f32x4 s = {h * w4[0], h * w4[1], h * w4[2], h * w4[3]};
  s = vaddv(s, shfl4(s, 1)); s = vaddv(s, shfl4(s, 2)); s = vaddv(s, shfl4(s, 4));
  s = vaddv(s, shfl4(s, 8)); s = vaddv(s, shfl4(s, 16)); s = vaddv(s, shfl4(s, 32));
  if (lane == 0) red2[wv] = s;
  __syncthreads();
  if (tid == 0){
    f32x4 lg = vaddv(vaddv(red2[0], red2[1]), vaddv(red2[2], red2[3]));
    float l4a[4]; float m = -3e38f;
    #pragma unroll
    for (int k = 0; k < 4; k++){ l4a[k] = lg[k] + rb2[k]; m = fmaxf(m, l4a[k]); }
    float ex[4]; float ssum2 = 0;
    #pragma unroll
    for (int k = 0; k < 4; k++){ ex[k] = expf(l4a[k] - m); ssum2 += ex[k]; }
    float gv[4];
    #pragma unroll
    for (int k = 0; k < 4; k++){ gv[k] = ex[k] / ssum2; gout[b * 4 + k] = gv[k]; }
    int i0 = 0; float v0 = gv[0];
    #pragma unroll
    for (int k = 1; k < 4; k++) if (gv[k] > v0){ v0 = gv[k]; i0 = k; }
    int i1 = -1; float v1 = -1.f;
    #pragma unroll
    for (int k = 0; k < 4; k++) if (k != i0 && gv[k] > v1){ v1 = gv[k]; i1 = k; }
    float den = v0 + v1 + 1e-8f;
    #pragma unroll
    for (int k = 0; k < 4; k++) wexp[k * BB + b] = (k == i0) ? (v0 / den) : ((k == i1) ? (v1 / den) : 0.f);
    pairs[2 * b]     = (i0 << 4) | b;
    pairs[2 * b + 1] = (i1 << 4) | b;
  }
}

// ---------------- final LN + pool, stage 1: grid (32 pairs, 8 chunks), 512 thr ----------------
__global__ __launch_bounds__(512) void lnf_partial(const u16* __restrict__ hin, const float* __restrict__ g,
                                                   const float* __restrict__ bta, float* __restrict__ part,
                                                   const int* __restrict__ pairs)
{
  const int p = blockIdx.x, chunk = blockIdx.y;
  const int pe = pairs[p];
  const int e = pe >> 4, b = pe & 15;
  const int tid = threadIdx.x, lane = tid & 63, wv = tid >> 6;
  __shared__ float gs[512], bsh[512];
  gs[tid] = g[e * DIM + tid]; bsh[tid] = bta[e * DIM + tid];
  __syncthreads();
  float acc[8] = {0, 0, 0, 0, 0, 0, 0, 0};
  #pragma unroll
  for (int i = 0; i < 8; i++){
    int n = chunk * 64 + i * 8 + wv;
    const u16* r = hin + ((long)e * ROWS + (long)b * NN + n) * DIM + lane * 8;
    u16x8 vh = *(const u16x8*)r;
    float v[8];
    #pragma unroll
    for (int j = 0; j < 8; j++) v[j] = h2f(vh[j]);
    float s = 0, sq = 0;
    #pragma unroll
    for (int j = 0; j < 8; j++){ s += v[j]; sq += v[j] * v[j]; }
    #pragma unroll
    for (int m = 32; m >= 1; m >>= 1){ s += __shfl_xor(s, m); sq += __shfl_xor(sq, m); }
    float mean = s * (1.f / DIM), var = sq * (1.f / DIM) - mean * mean, inv = rsqrtf(var + 1e-5f);
    #pragma unroll
    for (int j = 0; j < 8; j++) acc[j] += (v[j] - mean) * inv * gs[lane * 8 + j] + bsh[lane * 8 + j];
  }
  __shared__ float red[8][512];
  #pragma unroll
  for (int j = 0; j < 8; j++) red[wv][lane * 8 + j] = acc[j];
  __syncthreads();
  float ssum = 0;
  #pragma unroll
  for (int w = 0; w < 8; w++) ssum += red[w][tid];
  part[((long)p * 8 + chunk) * 512 + tid] = ssum;
}

// ---------------- final LN + pool, stage 2: grid 32, 512 thr ----------------
__global__ __launch_bounds__(512) void lnf_fin(const float* __restrict__ part, float* __restrict__ latents,
                                               const int* __restrict__ pairs)
{
  const int p = blockIdx.x;
  const int pe = pairs[p];
  const int e = pe >> 4, b = pe & 15;
  const int tid = threadIdx.x;
  float s = 0.f;
  #pragma unroll
  for (int c = 0; c < 8; c++) s += part[((long)p * 8 + c) * 512 + tid];
  latents[((long)e * BB + b) * DIM + tid] = s * (1.f / NN);
}

// ---------------- head layer-1 partial + z output: grid (16 b, 4 kc), 128 thr ----------------
__global__ __launch_bounds__(128) void head_l1(const float* __restrict__ latents, const float* __restrict__ wexp,
                                               const float* __restrict__ hw1, float* __restrict__ out,
                                               float* __restrict__ hidp2)
{
  const int b = blockIdx.x, kc = blockIdx.y;
  const int tid = threadIdx.x;
  __shared__ float zs[128];
  float wk[4];
  #pragma unroll
  for (int k = 0; k < 4; k++) wk[k] = wexp[k * BB + b];
  int c = kc * 128 + tid;
  float z = 0.f;
  #pragma unroll
  for (int k = 0; k < 4; k++) if (wk[k] != 0.f) z += wk[k] * latents[((long)k * BB + b) * DIM + c];
  zs[tid] = z;
  out[b * 512 + c] = z;
  __syncthreads();
  float a = 0.f;
  #pragma unroll 8
  for (int cc = 0; cc < 128; cc++) a += zs[cc] * hw1[(long)(kc * 128 + cc) * 128 + tid];
  hidp2[((long)b * 4 + kc) * 128 + tid] = a;
}

// ---------------- head final: reduce partials + relu + layer-2: grid 16, 128 thr ----------------
__global__ __launch_bounds__(128) void head_fin(const float* __restrict__ hidp2, const float* __restrict__ hb1,
                                                const float* __restrict__ hw2, const float* __restrict__ hb2,
                                                float* __restrict__ out)
{
  const int b = blockIdx.x;
  const int tid = threadIdx.x;
  __shared__ float hid[128];
  float h = hb1[tid];
  #pragma unroll
  for (int kc = 0; kc < 4; kc++) h += hidp2[((long)b * 4 + kc) * 128 + tid];
  hid[tid] = fmaxf(h, 0.f);
  __syncthreads();
  if (tid < 10){
    float s = hb2[tid];
    #pragma unroll 16
    for (int j = 0; j < 128; j++) s += hid[j] * hw2[j * 10 + tid];
    out[8192 + b * 10 + tid] = s;
  }
}

extern "C" void kernel_launch(void* const* d_in, const int* in_sizes, int n_in,
                              void* d_out, int out_size, void* d_ws, size_t ws_size,
                              hipStream_t stream)
{
  const float* x      = (const float*)d_in[0];
  const float* proj_w = (const float*)d_in[1];
  const float* proj_b = (const float*)d_in[2];
  const float* qkv_w  = (const float*)d_in[3];
  const float* ao_w   = (const float*)d_in[4];
  const float* ao_b   = (const float*)d_in[5];
  const float* ln1_g  = (const float*)d_in[6];
  const float* ln1_b  = (const float*)d_in[7];
  const float* ln2_g  = (const float*)d_in[8];
  const float* ln2_b  = (const float*)d_in[9];
  const float* mlp_w1 = (const float*)d_in[10];
  const float* mlp_b1 = (const float*)d_in[11];
  const float* mlp_w2 = (const float*)d_in[12];
  const float* mlp_b2 = (const float*)d_in[13];
  const float* lnf_g  = (const float*)d_in[14];
  const float* lnf_b  = (const float*)d_in[15];
  const float* rw1    = (const float*)d_in[16];
  const float* rb1    = (const float*)d_in[17];
  const float* rw2    = (const float*)d_in[18];
  const float* rb2    = (const float*)d_in[19];
  const float* hw1    = (const float*)d_in[20];
  const float* hb1    = (const float*)d_in[21];
  const float* hw2    = (const float*)d_in[22];
  const float* hb2    = (const float*)d_in[23];
  float* out = (float*)d_out;

  char* base = (char*)d_ws; size_t off = 0;
  auto alloc = [&](size_t bytes) -> void* { void* p = base + off; off = (off + bytes + 255) & ~(size_t)255; return p; };

  u16* WQ   = (u16*)alloc((size_t)8 * 1536 * 512 * 2);
  u16* WAO  = (u16*)alloc((size_t)8 * 512 * 512 * 2);
  u16* W1t  = (u16*)alloc((size_t)8 * 512 * 512 * 2);
  u16* W2t  = (u16*)alloc((size_t)8 * 512 * 512 * 2);
  u16* WP   = (u16*)alloc((size_t)512 * 2048 * 2);
  u16* HF   = (u16*)alloc((size_t)ROWS * 512 * 2);
  u16* HH   = (u16*)alloc((size_t)4 * ROWS * 512 * 2);
  u16* YB   = (u16*)alloc((size_t)4 * ROWS * 512 * 2);
  u16* QKVb = (u16*)alloc((size_t)4 * ROWS * 1536 * 2);
  float* WEXP = (float*)alloc(64 * 4);
  int* PAIRS  = (int*)alloc(32 * 4);
  float* LAT  = (float*)alloc(4 * 16 * 512 * 4);
  float* BAGP = (float*)alloc((size_t)8 * 16 * 512 * 4);
  float* HIDP = (float*)alloc((size_t)16 * 8 * 256 * 4);
  float* PART = (float*)alloc((size_t)32 * 8 * 512 * 4);
  float* HIDP2 = (float*)alloc((size_t)16 * 4 * 128 * 4);
  u16* Y2B = QKVb;
  u16* TB  = QKVb + (size_t)4 * ROWS * 512;
  u16* OB  = YB;
  u16* Xf  = QKVb;  // dead until first qkv GEMM; proj consumes it before that

  castAll<<<dim3(16, 48, 32), 256, 0, stream>>>(qkv_w, ao_w, mlp_w1, mlp_w2, WQ, WAO, W1t, W2t);
  castTp<<<dim3(64, 16), 256, 0, stream>>>(proj_w, WP);
  xcast<<<8192, 256, 0, stream>>>(x, Xf);

  gemm_proj<<<dim3(128, 4), 256, 0, stream>>>(Xf, WP, proj_b, HF);
  bag_partial<<<dim3(16, 8), 512, 0, stream>>>(HF, BAGP);
  router_mm<<<dim3(8, 16), 256, 0, stream>>>(BAGP, rw1, HIDP);
  router_fin<<<16, 256, 0, stream>>>(HIDP, rb1, rw2, rb2, out + 8192 + 160, WEXP, PAIRS);

  for (int l = 0; l < 2; l++){
    if (l == 0)
      ln_rows<<<4096, 256, 0, stream>>>(HF, 0L, ln1_g, ln1_b, DEP * 512, YB, PAIRS);
    else
      ln_rows<<<4096, 256, 0, stream>>>(HH, ROWS * 512, ln1_g + 512, ln1_b + 512, DEP * 512, YB, PAIRS);
    gemm_bt<0, 128><<<dim3(128, 12), 256, 0, stream>>>(YB, 512, ROWS * 512, WQ + (long)l * 1536 * 512, (long)DEP * 1536 * 512,
                                                       nullptr, 0, QKVb, ROWS * 1536, 1536, PAIRS, nullptr);
    attn<<<1024, 256, 0, stream>>>(QKVb, OB, PAIRS);
    if (l == 0)
      gemm_bt<3, 64><<<dim3(256, 4), 256, 0, stream>>>(OB, 512, ROWS * 512, WAO, (long)DEP * 512 * 512,
                                                       ao_b, DEP * 512, HH, ROWS * 512, 512, PAIRS, HF);
    else
      gemm_bt<2, 64><<<dim3(256, 4), 256, 0, stream>>>(OB, 512, ROWS * 512, WAO + (long)512 * 512, (long)DEP * 512 * 512,
                                                       ao_b + 512, DEP * 512, HH, ROWS * 512, 512, PAIRS, nullptr);
    ln_rows<<<4096, 256, 0, stream>>>(HH, ROWS * 512, ln2_g + l * 512, ln2_b + l * 512, DEP * 512, Y2B, PAIRS);
    gemm_bt<1, 64><<<dim3(256, 4), 256, 0, stream>>>(Y2B, 512, ROWS * 512, W1t + (long)l * 512 * 512, (long)DEP * 512 * 512,
                                                     mlp_b1 + l * 512, DEP * 512, TB, ROWS * 512, 512, PAIRS, nullptr);
    gemm_bt<2, 64><<<dim3(256, 4), 256, 0, stream>>>(TB, 512, ROWS * 512, W2t + (long)l * 512 * 512, (long)DEP * 512 * 512,
                                                     mlp_b2 + l * 512, DEP * 512, HH, ROWS * 512, 512, PAIRS, nullptr);
  }

  lnf_partial<<<dim3(32, 8), 512, 0, stream>>>(HH, lnf_g, lnf_b, PART, PAIRS);
  lnf_fin<<<32, 512, 0, stream>>>(PART, LAT, PAIRS);
  head_l1<<<dim3(16, 4), 128, 0, stream>>>(LAT, WEXP, hw1, out, HIDP2);
  head_fin<<<16, 128, 0, stream>>>(HIDP2, hb1, hw2, hb2, out);
}

// Round 12
// 412.861 us; speedup vs baseline: 1.0538x; 1.0538x over previous
//
#include <hip/hip_runtime.h>
#include <math.h>

typedef unsigned short u16;
typedef unsigned int u32;
typedef float f32x4 __attribute__((ext_vector_type(4)));
typedef unsigned short u16x8 __attribute__((ext_vector_type(8)));
typedef unsigned short u16x4 __attribute__((ext_vector_type(4)));
typedef _Float16 f16x8 __attribute__((ext_vector_type(8)));
typedef _Float16 f16x4 __attribute__((ext_vector_type(4)));

#define DEV static __device__ __forceinline__

constexpr int BB = 16, NN = 512, DIM = 512, DEP = 2;
constexpr long ROWS = (long)BB * NN;  // 8192

DEV u16 f2h(float f){ _Float16 h = (_Float16)f; return __builtin_bit_cast(u16, h); }
DEV float h2f(u16 u){ return (float)__builtin_bit_cast(_Float16, u); }
DEV f32x4 mfma16h(u16x8 a, u16x8 b, f32x4 c){
  return __builtin_amdgcn_mfma_f32_16x16x32_f16(__builtin_bit_cast(f16x8, a), __builtin_bit_cast(f16x8, b), c, 0, 0, 0);
}
DEV u32 pkrtz(float a, float b){ auto r = __builtin_amdgcn_cvt_pkrtz(a, b); return __builtin_bit_cast(u32, r); }
DEV u16x4 cvt4(f32x4 a){ f16x4 h = {(_Float16)a[0], (_Float16)a[1], (_Float16)a[2], (_Float16)a[3]}; return __builtin_bit_cast(u16x4, h); }
DEV float gelu_f(float x){ return 0.5f * x * (1.f + tanhf(0.79788456080286536f * (x + 0.044715f * x * x * x))); }

// async global->LDS, 16B per lane. LDS dest is wave-uniform base + lane*16 (m104).
DEV void gload16(const u16* g, u16* l){
  __builtin_amdgcn_global_load_lds((const __attribute__((address_space(1))) unsigned int*)(const void*)g,
                                   (__attribute__((address_space(3))) unsigned int*)(void*)l, 16, 0, 0);
}

DEV f32x4 vaddv(f32x4 a, f32x4 b){ f32x4 r; r[0]=a[0]+b[0]; r[1]=a[1]+b[1]; r[2]=a[2]+b[2]; r[3]=a[3]+b[3]; return r; }
DEV f32x4 shfl4(f32x4 v, int m){ f32x4 r; r[0]=__shfl_xor(v[0],m); r[1]=__shfl_xor(v[1],m); r[2]=__shfl_xor(v[2],m); r[3]=__shfl_xor(v[3],m); return r; }

// ---------------- all expert weight transpose-casts (f32 -> f16, [K][N] -> [N][K]) ----------------
__global__ __launch_bounds__(256) void castAll(const float* __restrict__ qkv_w, const float* __restrict__ ao_w,
                                               const float* __restrict__ mlp_w1, const float* __restrict__ mlp_w2,
                                               u16* __restrict__ WQ, u16* __restrict__ WAO,
                                               u16* __restrict__ W1t, u16* __restrict__ W2t)
{
  const int z = blockIdx.z;
  const float* src; u16* dst; int Nd;
  if (z < 8){ src = qkv_w + (long)z * 512 * 1536; dst = WQ + (long)z * 512 * 1536; Nd = 1536; }
  else {
    int m = (z - 8) >> 3, zz = (z - 8) & 7;
    src = (m == 0 ? ao_w : m == 1 ? mlp_w1 : mlp_w2) + (long)zz * 512 * 512;
    dst = (m == 0 ? WAO : m == 1 ? W1t : W2t) + (long)zz * 512 * 512;
    Nd = 512;
  }
  const int n0 = blockIdx.y * 32;
  if (n0 >= Nd) return;
  const int k0 = blockIdx.x * 32;
  __shared__ float t[32][33];
  const int r = threadIdx.x >> 5, cc = threadIdx.x & 31;
  #pragma unroll
  for (int i = 0; i < 4; i++) t[r + i * 8][cc] = src[(long)(k0 + r + i * 8) * Nd + n0 + cc];
  __syncthreads();
  #pragma unroll
  for (int i = 0; i < 4; i++) dst[(long)(n0 + r + i * 8) * 512 + k0 + cc] = f2h(t[cc][r + i * 8]);
}

// ---------------- proj weight: [2048][512] f32 -> [512][2048] f16 ----------------
__global__ __launch_bounds__(256) void castTp(const float* __restrict__ src, u16* __restrict__ dst)
{
  __shared__ float t[32][33];
  const int k0 = blockIdx.x * 32, n0 = blockIdx.y * 32;
  const int r = threadIdx.x >> 5, cc = threadIdx.x & 31;
  #pragma unroll
  for (int i = 0; i < 4; i++) t[r + i * 8][cc] = src[(long)(k0 + r + i * 8) * 512 + n0 + cc];
  __syncthreads();
  #pragma unroll
  for (int i = 0; i < 4; i++) dst[(long)(n0 + r + i * 8) * 2048 + k0 + cc] = f2h(t[cc][r + i * 8]);
}

// ---------------- X f32 -> f16 ----------------
__global__ __launch_bounds__(256) void xcast(const float* __restrict__ X, u16* __restrict__ Xf)
{
  long i0 = ((long)blockIdx.x * 256 + threadIdx.x) * 8;
  f32x4 v0 = *(const f32x4*)(X + i0), v1 = *(const f32x4*)(X + i0 + 4);
  u16x8 hh;
  hh[0] = f2h(v0[0]); hh[1] = f2h(v0[1]); hh[2] = f2h(v0[2]); hh[3] = f2h(v0[3]);
  hh[4] = f2h(v1[0]); hh[5] = f2h(v1[1]); hh[6] = f2h(v1[2]); hh[7] = f2h(v1[3]);
  *(u16x8*)(Xf + i0) = hh;
}

// ---------------- proj GEMM: H[8192,512] = Xf @ WP^T + bias, f16 out ----------------
__global__ __launch_bounds__(256) void gemm_proj(const u16* __restrict__ Xf, const u16* __restrict__ WP,
                                                 const float* __restrict__ bias, u16* __restrict__ Hout)
{
  const int mt = blockIdx.x, nt = blockIdx.y;
  __shared__ __align__(16) u16 As[64 * 64], Bs[128 * 64];
  const int tid = threadIdx.x, lane = tid & 63, wv = tid >> 6;
  const int wm = wv >> 1, wn = wv & 1, l4 = lane >> 4, l15 = lane & 15;
  const long a0 = (long)(mt * 64) * 2048, b0 = (long)(nt * 128) * 2048;
  const int srow = tid >> 3, sslot = tid & 7;
  f32x4 zero = {0.f, 0.f, 0.f, 0.f};
  f32x4 acc[2][4];
  #pragma unroll
  for (int mi = 0; mi < 2; mi++)
    #pragma unroll
    for (int ni = 0; ni < 4; ni++) acc[mi][ni] = zero;

  for (int kt = 0; kt < 2048; kt += 64){
    #pragma unroll
    for (int p = 0; p < 2; p++){
      int r = p * 32 + srow;
      int sg = sslot ^ (r & 7);
      gload16(Xf + a0 + (long)r * 2048 + kt + sg * 8, As + p * 2048 + wv * 512);
    }
    #pragma unroll
    for (int p = 0; p < 4; p++){
      int r = p * 32 + srow;
      int sg = sslot ^ (r & 7);
      gload16(WP + b0 + (long)r * 2048 + kt + sg * 8, Bs + p * 2048 + wv * 512);
    }
    __syncthreads();
    #pragma unroll
    for (int ks = 0; ks < 2; ks++){
      u16x8 af[2], bfr[4];
      #pragma unroll
      for (int mi = 0; mi < 2; mi++){
        int ra = wm * 32 + mi * 16 + l15;
        af[mi] = *(const u16x8*)(As + ra * 64 + ((((ks << 2) | l4)) ^ (ra & 7)) * 8);
      }
      #pragma unroll
      for (int ni = 0; ni < 4; ni++){
        int rb = wn * 64 + ni * 16 + l15;
        bfr[ni] = *(const u16x8*)(Bs + rb * 64 + ((((ks << 2) | l4)) ^ (rb & 7)) * 8);
      }
      #pragma unroll
      for (int mi = 0; mi < 2; mi++)
        #pragma unroll
        for (int ni = 0; ni < 4; ni++)
          acc[mi][ni] = mfma16h(af[mi], bfr[ni], acc[mi][ni]);
    }
    __syncthreads();
  }
  #pragma unroll
  for (int mi = 0; mi < 2; mi++)
    #pragma unroll
    for (int ni = 0; ni < 4; ni++){
      const int gr0 = mt * 64 + wm * 32 + mi * 16 + l4 * 4;
      const int gc = nt * 128 + wn * 64 + ni * 16 + l15;
      float bb = bias[gc];
      #pragma unroll
      for (int i = 0; i < 4; i++) Hout[(long)(gr0 + i) * 512 + gc] = f2h(acc[mi][ni][i] + bb);
    }
}

// ---------------- generic f16 GEMM over compacted (e,b) pairs (non-swapped, R10 epilogue) ----------------
// MT = M-tile rows (128 or 64). grid.x = 32 * (512/MT), grid.y = N/128.
// EPI: 0 = f16 out (+bias), 1 = f16 gelu out, 2 = f16 residual RMW, 3 = f16 out = resin + acc + bias
template<int EPI, int MT>
__global__ __launch_bounds__(256) void gemm_bt(const u16* __restrict__ A, int K, long sAe,
                                               const u16* __restrict__ Bt, long sBe,
                                               const float* __restrict__ bias, int sBiasE,
                                               u16* __restrict__ Cout, long sCe, int N,
                                               const int* __restrict__ pairs,
                                               const u16* __restrict__ resin)
{
  constexpr int MI = MT / 32;          // a-frags per wave == staging iterations
  constexpr int PSH = (MT == 128) ? 2 : 3;
  const int pe = pairs[blockIdx.x >> PSH];
  const int e = pe >> 4, bb = pe & 15;
  const int row0 = bb * 512 + (blockIdx.x & ((1 << PSH) - 1)) * MT;
  const int nt = blockIdx.y;
  A += (long)e * sAe + (long)row0 * K;
  Bt += (long)e * sBe + (long)(nt * 128) * K;
  const float* bias_e = bias ? bias + (long)e * sBiasE : nullptr;

  __shared__ __align__(16) u16 As[MT * 64];
  __shared__ __align__(16) u16 Bs[128 * 64];
  const int tid = threadIdx.x, lane = tid & 63, wv = tid >> 6;
  const int wm = wv >> 1, wn = wv & 1, l4 = lane >> 4, l15 = lane & 15;
  const int srow = tid >> 3, sslot = tid & 7;
  f32x4 zero = {0.f, 0.f, 0.f, 0.f};
  f32x4 acc[MI][4];
  #pragma unroll
  for (int mi = 0; mi < MI; mi++)
    #pragma unroll
    for (int ni = 0; ni < 4; ni++) acc[mi][ni] = zero;

  for (int kt = 0; kt < K; kt += 64){
    #pragma unroll
    for (int p = 0; p < MI; p++){
      int r = p * 32 + srow;
      int sg = sslot ^ (r & 7);
      gload16(A + (long)r * K + kt + sg * 8, As + p * 2048 + wv * 512);
    }
    #pragma unroll
    for (int p = 0; p < 4; p++){
      int r = p * 32 + srow;
      int sg = sslot ^ (r & 7);
      gload16(Bt + (long)r * K + kt + sg * 8, Bs + p * 2048 + wv * 512);
    }
    __syncthreads();
    #pragma unroll
    for (int ks = 0; ks < 2; ks++){
      u16x8 af[MI], bfr[4];
      #pragma unroll
      for (int mi = 0; mi < MI; mi++){
        int ra = wm * (MT / 2) + mi * 16 + l15;
        af[mi] = *(const u16x8*)(As + ra * 64 + ((((ks << 2) | l4)) ^ (ra & 7)) * 8);
      }
      #pragma unroll
      for (int ni = 0; ni < 4; ni++){
        int rb = wn * 64 + ni * 16 + l15;
        bfr[ni] = *(const u16x8*)(Bs + rb * 64 + ((((ks << 2) | l4)) ^ (rb & 7)) * 8);
      }
      #pragma unroll
      for (int mi = 0; mi < MI; mi++)
        #pragma unroll
        for (int ni = 0; ni < 4; ni++)
          acc[mi][ni] = mfma16h(af[mi], bfr[ni], acc[mi][ni]);
    }
    __syncthreads();
  }

  #pragma unroll
  for (int mi = 0; mi < MI; mi++)
    #pragma unroll
    for (int ni = 0; ni < 4; ni++){
      const int gr0 = row0 + wm * (MT / 2) + mi * 16 + l4 * 4;
      const int gc = nt * 128 + wn * 64 + ni * 16 + l15;
      float bb2 = bias_e ? bias_e[gc] : 0.f;
      #pragma unroll
      for (int i = 0; i < 4; i++){
        float val = acc[mi][ni][i] + bb2;
        long idx = (long)e * sCe + (long)(gr0 + i) * N + gc;
        if (EPI == 0){
          Cout[idx] = f2h(val);
        } else if (EPI == 1){
          Cout[idx] = f2h(gelu_f(val));
        } else if (EPI == 2){
          Cout[idx] = f2h(h2f(Cout[idx]) + val);
        } else {
          Cout[idx] = f2h(h2f(resin[(long)(gr0 + i) * N + gc]) + val);
        }
      }
    }
}

// ---------------- flash attention, swapped-QK + swapped-PV, f16, compacted pairs ----------------
// grid = 1024, XCD-friendly order: p = bx&31, hh = (bx>>5)&7, qt = bx>>8.
__global__ __launch_bounds__(256) void attn(const u16* __restrict__ qkv, u16* __restrict__ obf, const int* __restrict__ pairs)
{
  const int pe = pairs[blockIdx.x & 31];
  const int e = pe >> 4, b = pe & 15;
  const int hh = (blockIdx.x >> 5) & 7;
  const int qt = blockIdx.x >> 8;
  const u16* base = qkv + ((long)e * ROWS + (long)b * NN) * 1536;

  __shared__ u16 Ks[64 * 72];
  __shared__ u16 Vts[64 * 72];
  __shared__ u16 Ps[4][32 * 72];
  const int tid = threadIdx.x, lane = tid & 63, wv = tid >> 6;
  const int l4 = lane >> 4, l15 = lane & 15;
  const int qr0 = qt * 128 + wv * 32;
  constexpr float CSC = 0.125f * 1.44269504088896340736f;

  u16x8 qf[2][2];
  #pragma unroll
  for (int mi = 0; mi < 2; mi++)
    #pragma unroll
    for (int ks = 0; ks < 2; ks++){
      u16x8 raw = *(const u16x8*)(base + (long)(qr0 + mi * 16 + l15) * 1536 + hh * 64 + ks * 32 + l4 * 8);
      #pragma unroll
      for (int j = 0; j < 8; j++) qf[mi][ks][j] = f2h(h2f(raw[j]) * CSC);
    }

  f32x4 zero = {0.f, 0.f, 0.f, 0.f};
  f32x4 o[2][4]; float lrun[2] = {0.f, 0.f};
  #pragma unroll
  for (int mi = 0; mi < 2; mi++)
    #pragma unroll
    for (int df = 0; df < 4; df++) o[mi][df] = zero;
  const int sr = tid >> 3, ss = tid & 7;

  for (int c = 0; c < 8; c++){
    const int kk0 = c * 64;
    u16x8 kv0 = *(const u16x8*)(base + (long)(kk0 + sr) * 1536 + 512 + hh * 64 + ss * 8);
    u16x8 kv1 = *(const u16x8*)(base + (long)(kk0 + sr + 32) * 1536 + 512 + hh * 64 + ss * 8);
    u16x8 vv0 = *(const u16x8*)(base + (long)(kk0 + sr) * 1536 + 1024 + hh * 64 + ss * 8);
    u16x8 vv1 = *(const u16x8*)(base + (long)(kk0 + sr + 32) * 1536 + 1024 + hh * 64 + ss * 8);
    __syncthreads();
    *(u16x8*)(Ks + sr * 72 + ss * 8) = kv0;
    *(u16x8*)(Ks + (sr + 32) * 72 + ss * 8) = kv1;
    #pragma unroll
    for (int j = 0; j < 8; j++){
      int d = ss * 8 + j;
      Vts[d * 72 + (sr ^ (ss * 8))] = vv0[j];
      Vts[d * 72 + ((sr + 32) ^ (ss * 8))] = vv1[j];
    }
    __syncthreads();

    u16x8 kf[4][2];
    #pragma unroll
    for (int n = 0; n < 4; n++)
      #pragma unroll
      for (int ks = 0; ks < 2; ks++)
        kf[n][ks] = *(const u16x8*)(Ks + (n * 16 + l15) * 72 + ks * 32 + l4 * 8);

    f32x4 sv[2][4];
    __builtin_amdgcn_s_setprio(1);
    #pragma unroll
    for (int mi = 0; mi < 2; mi++)
      #pragma unroll
      for (int n = 0; n < 4; n++){
        sv[mi][n] = zero;
        sv[mi][n] = mfma16h(kf[n][0], qf[mi][0], sv[mi][n]);
        sv[mi][n] = mfma16h(kf[n][1], qf[mi][1], sv[mi][n]);
      }
    __builtin_amdgcn_s_setprio(0);

    #pragma unroll
    for (int mi = 0; mi < 2; mi++){
      float lp = 0.f;
      #pragma unroll
      for (int n = 0; n < 4; n++){
        float p0 = __builtin_amdgcn_exp2f(sv[mi][n][0]);
        float p1 = __builtin_amdgcn_exp2f(sv[mi][n][1]);
        float p2 = __builtin_amdgcn_exp2f(sv[mi][n][2]);
        float p3 = __builtin_amdgcn_exp2f(sv[mi][n][3]);
        lp += (p0 + p1) + (p2 + p3);
        union { u32 w[2]; u16x4 h; } pk;
        pk.w[0] = pkrtz(p0, p1);
        pk.w[1] = pkrtz(p2, p3);
        *(u16x4*)(&Ps[wv][(mi * 16 + l15) * 72 + n * 16 + l4 * 4]) = pk.h;
      }
      lp += __shfl_xor(lp, 16);
      lp += __shfl_xor(lp, 32);
      lrun[mi] += lp;
    }

    u16x8 pf[2][2], vf[4][2];
    #pragma unroll
    for (int mi = 0; mi < 2; mi++)
      #pragma unroll
      for (int k2 = 0; k2 < 2; k2++)
        pf[mi][k2] = *(const u16x8*)(&Ps[wv][(mi * 16 + l15) * 72 + k2 * 32 + l4 * 8]);
    #pragma unroll
    for (int df = 0; df < 4; df++)
      #pragma unroll
      for (int k2 = 0; k2 < 2; k2++){
        int d = df * 16 + l15;
        int swz = ((d >> 3) & 7) * 8;
        vf[df][k2] = *(const u16x8*)(Vts + d * 72 + ((k2 * 32 + l4 * 8) ^ swz));
      }
    // swapped PV: o rows = d (l4*4+i), cols = q (l15)
    __builtin_amdgcn_s_setprio(1);
    #pragma unroll
    for (int mi = 0; mi < 2; mi++)
      #pragma unroll
      for (int df = 0; df < 4; df++){
        o[mi][df] = mfma16h(vf[df][0], pf[mi][0], o[mi][df]);
        o[mi][df] = mfma16h(vf[df][1], pf[mi][1], o[mi][df]);
      }
    __builtin_amdgcn_s_setprio(0);
  }

  // q = qr0 + mi*16 + l15 matches lrun[mi]'s lane -> no LDS roundtrip
  #pragma unroll
  for (int mi = 0; mi < 2; mi++){
    float inv = 1.f / lrun[mi];
    long rb = (long)e * ROWS * DIM + (long)(b * NN + qr0 + mi * 16 + l15) * DIM + hh * 64;
    #pragma unroll
    for (int df = 0; df < 4; df++){
      f32x4 a;
      #pragma unroll
      for (int i = 0; i < 4; i++) a[i] = o[mi][df][i] * inv;
      *(u16x4*)(obf + rb + df * 16 + l4 * 4) = cvt4(a);
    }
  }
}

// ---------------- LayerNorm rows (f16 in, f16 out), one wave per row, vectorized: grid = 4096 ----------------
__global__ __launch_bounds__(256) void ln_rows(const u16* __restrict__ hin, long sHe,
                                               const float* __restrict__ g, const float* __restrict__ bta,
                                               int sGE, u16* __restrict__ outb, const int* __restrict__ pairs)
{
  const int pe = pairs[blockIdx.x >> 7];
  const int e = pe >> 4;
  const int tid = threadIdx.x, lane = tid & 63, wv = tid >> 6;
  const int row = (pe & 15) * 512 + ((blockIdx.x & 127) << 2) + wv;
  const u16* x = hin + (long)e * sHe + (long)row * DIM + lane * 8;
  u16x8 vh = *(const u16x8*)x;
  float v[8];
  #pragma unroll
  for (int j = 0; j < 8; j++) v[j] = h2f(vh[j]);
  float s = 0.f, sq = 0.f;
  #pragma unroll
  for (int j = 0; j < 8; j++){ s += v[j]; sq += v[j] * v[j]; }
  #pragma unroll
  for (int m = 32; m >= 1; m >>= 1){ s += __shfl_xor(s, m); sq += __shfl_xor(sq, m); }
  float mean = s * (1.f / DIM); float var = sq * (1.f / DIM) - mean * mean;
  float inv = rsqrtf(var + 1e-5f);
  const float* ge = g + (long)e * sGE + lane * 8;
  const float* be = bta + (long)e * sGE + lane * 8;
  f32x4 g0 = *(const f32x4*)ge, g1 = *(const f32x4*)(ge + 4);
  f32x4 b0 = *(const f32x4*)be, b1 = *(const f32x4*)(be + 4);
  u16x8 yo;
  #pragma unroll
  for (int j = 0; j < 4; j++) yo[j] = f2h((v[j] - mean) * inv * g0[j] + b0[j]);
  #pragma unroll
  for (int j = 0; j < 4; j++) yo[4 + j] = f2h((v[4 + j] - mean) * inv * g1[j] + b1[j]);
  *(u16x8*)(outb + ((long)e * ROWS + row) * DIM + lane * 8) = yo;
}

// ---------------- bag stage 1: partial means. grid (16 b, 8 c), 512 thr ----------------
__global__ __launch_bounds__(512) void bag_partial(const u16* __restrict__ H, float* __restrict__ bagp)
{
  const int b = blockIdx.x, c = blockIdx.y;
  const int tid = threadIdx.x;
  const u16* r = H + ((long)b * 512 + c * 64) * DIM + tid;
  float s = 0.f;
  #pragma unroll 8
  for (int n = 0; n < 64; n++) s += h2f(r[n * DIM]);
  bagp[((long)c * BB + b) * DIM + tid] = s;
}

// ---------------- router stage 2: partial layer-1. grid (8 kc, 16 b), 256 thr ----------------
__global__ __launch_bounds__(256) void router_mm(const float* __restrict__ bagp, const float* __restrict__ rw1,
                                                 float* __restrict__ hidp)
{
  const int kc = blockIdx.x, b = blockIdx.y;
  const int tid = threadIdx.x;
  __shared__ float bs[64];
  if (tid < 64){
    int k = kc * 64 + tid;
    float s = 0.f;
    #pragma unroll
    for (int c = 0; c < 8; c++) s += bagp[((long)c * BB + b) * DIM + k];
    bs[tid] = s * (1.f / NN);
  }
  __syncthreads();
  float a = 0.f;
  #pragma unroll 8
  for (int k = 0; k < 64; k++) a += bs[k] * rw1[(long)(kc * 64 + k) * 256 + tid];
  hidp[((long)b * 8 + kc) * 256 + tid] = a;
}

// ---------------- router stage 3: reduce + relu + layer2 + softmax + top2 + PAIRS. 16 blocks, 256 thr ----------------
__global__ __launch_bounds__(256) void router_fin(const float* __restrict__ hidp,
                                                  const float* __restrict__ rb1,
                                                  const float* __restrict__ rw2, const float* __restrict__ rb2,
                                                  float* __restrict__ gout, float* __restrict__ wexp, int* __restrict__ pairs)
{
  const int b = blockIdx.x;
  const int tid = threadIdx.x, lane = tid & 63, wv = tid >> 6;
  __shared__ f32x4 red2[4];
  float a = rb1[tid];
  #pragma unroll
  for (int kc = 0; kc < 8; kc++) a += hidp[((long)b * 8 + kc) * 256 + tid];
  float h = fmaxf(a, 0.f);
  f32x4 w4 = *(const f32x4*)(rw2 + tid * 4);
  f32x4 s = {h * w4[0], h * w4[1], h * w4[2], h * w4[3]};
  s = vaddv(s, shfl4(s, 1)); s = vaddv(s, shfl4(s, 2)); s = vaddv(s, shfl4(s, 4));
  s = vaddv(s, shfl4(s, 8)); s = vaddv(s, shfl4(s, 16)); s = vaddv(s, shfl4(s, 32));
  if (lane == 0) red2[wv] = s;
  __syncthreads();
  if (tid == 0){
    f32x4 lg = vaddv(vaddv(red2[0], red2[1]), vaddv(red2[2], red2[3]));
    float l4a[4]; float m = -3e38f;
    #pragma unroll
    for (int k = 0; k < 4; k++){ l4a[k] = lg[k] + rb2[k]; m = fmaxf(m, l4a[k]); }
    float ex[4]; float ssum2 = 0;
    #pragma unroll
    for (int k = 0; k < 4; k++){ ex[k] = expf(l4a[k] - m); ssum2 += ex[k]; }
    float gv[4];
    #pragma unroll
    for (int k = 0; k < 4; k++){ gv[k] = ex[k] / ssum2; gout[b * 4 + k] = gv[k]; }
    int i0 = 0; float v0 = gv[0];
    #pragma unroll
    for (int k = 1; k < 4; k++) if (gv[k] > v0){ v0 = gv[k]; i0 = k; }
    int i1 = -1; float v1 = -1.f;
    #pragma unroll
    for (int k = 0; k < 4; k++) if (k != i0 && gv[k] > v1){ v1 = gv[k]; i1 = k; }
    float den = v0 + v1 + 1e-8f;
    #pragma unroll
    for (int k = 0; k < 4; k++) wexp[k * BB + b] = (k == i0) ? (v0 / den) : ((k == i1) ? (v1 / den) : 0.f);
    pairs[2 * b]     = (i0 << 4) | b;
    pairs[2 * b + 1] = (i1 << 4) | b;
  }
}

// ---------------- final LN + pool, stage 1: grid (32 pairs, 8 chunks), 512 thr ----------------
__global__ __launch_bounds__(512) void lnf_partial(const u16* __restrict__ hin, const float* __restrict__ g,
                                                   const float* __restrict__ bta, float* __restrict__ part,
                                                   const int* __restrict__ pairs)
{
  const int p = blockIdx.x, chunk = blockIdx.y;
  const int pe = pairs[p];
  const int e = pe >> 4, b = pe & 15;
  const int tid = threadIdx.x, lane = tid & 63, wv = tid >> 6;
  __shared__ float gs[512], bsh[512];
  gs[tid] = g[e * DIM + tid]; bsh[tid] = bta[e * DIM + tid];
  __syncthreads();
  float acc[8] = {0, 0, 0, 0, 0, 0, 0, 0};
  #pragma unroll
  for (int i = 0; i < 8; i++){
    int n = chunk * 64 + i * 8 + wv;
    const u16* r = hin + ((long)e * ROWS + (long)b * NN + n) * DIM + lane * 8;
    u16x8 vh = *(const u16x8*)r;
    float v[8];
    #pragma unroll
    for (int j = 0; j < 8; j++) v[j] = h2f(vh[j]);
    float s = 0, sq = 0;
    #pragma unroll
    for (int j = 0; j < 8; j++){ s += v[j]; sq += v[j] * v[j]; }
    #pragma unroll
    for (int m = 32; m >= 1; m >>= 1){ s += __shfl_xor(s, m); sq += __shfl_xor(sq, m); }
    float mean = s * (1.f / DIM), var = sq * (1.f / DIM) - mean * mean, inv = rsqrtf(var + 1e-5f);
    #pragma unroll
    for (int j = 0; j < 8; j++) acc[j] += (v[j] - mean) * inv * gs[lane * 8 + j] + bsh[lane * 8 + j];
  }
  __shared__ float red[8][512];
  #pragma unroll
  for (int j = 0; j < 8; j++) red[wv][lane * 8 + j] = acc[j];
  __syncthreads();
  float ssum = 0;
  #pragma unroll
  for (int w = 0; w < 8; w++) ssum += red[w][tid];
  part[((long)p * 8 + chunk) * 512 + tid] = ssum;
}

// ---------------- final LN + pool, stage 2: grid 32, 512 thr ----------------
__global__ __launch_bounds__(512) void lnf_fin(const float* __restrict__ part, float* __restrict__ latents,
                                               const int* __restrict__ pairs)
{
  const int p = blockIdx.x;
  const int pe = pairs[p];
  const int e = pe >> 4, b = pe & 15;
  const int tid = threadIdx.x;
  float s = 0.f;
  #pragma unroll
  for (int c = 0; c < 8; c++) s += part[((long)p * 8 + c) * 512 + tid];
  latents[((long)e * BB + b) * DIM + tid] = s * (1.f / NN);
}

// ---------------- head layer-1 partial + z output: grid (16 b, 4 kc), 128 thr ----------------
__global__ __launch_bounds__(128) void head_l1(const float* __restrict__ latents, const float* __restrict__ wexp,
                                               const float* __restrict__ hw1, float* __restrict__ out,
                                               float* __restrict__ hidp2)
{
  const int b = blockIdx.x, kc = blockIdx.y;
  const int tid = threadIdx.x;
  __shared__ float zs[128];
  float wk[4];
  #pragma unroll
  for (int k = 0; k < 4; k++) wk[k] = wexp[k * BB + b];
  int c = kc * 128 + tid;
  float z = 0.f;
  #pragma unroll
  for (int k = 0; k < 4; k++) if (wk[k] != 0.f) z += wk[k] * latents[((long)k * BB + b) * DIM + c];
  zs[tid] = z;
  out[b * 512 + c] = z;
  __syncthreads();
  float a = 0.f;
  #pragma unroll 8
  for (int cc = 0; cc < 128; cc++) a += zs[cc] * hw1[(long)(kc * 128 + cc) * 128 + tid];
  hidp2[((long)b * 4 + kc) * 128 + tid] = a;
}

// ---------------- head final: reduce partials + relu + layer-2: grid 16, 128 thr ----------------
__global__ __launch_bounds__(128) void head_fin(const float* __restrict__ hidp2, const float* __restrict__ hb1,
                                                const float* __restrict__ hw2, const float* __restrict__ hb2,
                                                float* __restrict__ out)
{
  const int b = blockIdx.x;
  const int tid = threadIdx.x;
  __shared__ float hid[128];
  float h = hb1[tid];
  #pragma unroll
  for (int kc = 0; kc < 4; kc++) h += hidp2[((long)b * 4 + kc) * 128 + tid];
  hid[tid] = fmaxf(h, 0.f);
  __syncthreads();
  if (tid < 10){
    float s = hb2[tid];
    #pragma unroll 16
    for (int j = 0; j < 128; j++) s += hid[j] * hw2[j * 10 + tid];
    out[8192 + b * 10 + tid] = s;
  }
}

extern "C" void kernel_launch(void* const* d_in, const int* in_sizes, int n_in,
                              void* d_out, int out_size, void* d_ws, size_t ws_size,
                              hipStream_t stream)
{
  const float* x      = (const float*)d_in[0];
  const float* proj_w = (const float*)d_in[1];
  const float* proj_b = (const float*)d_in[2];
  const float* qkv_w  = (const float*)d_in[3];
  const float* ao_w   = (const float*)d_in[4];
  const float* ao_b   = (const float*)d_in[5];
  const float* ln1_g  = (const float*)d_in[6];
  const float* ln1_b  = (const float*)d_in[7];
  const float* ln2_g  = (const float*)d_in[8];
  const float* ln2_b  = (const float*)d_in[9];
  const float* mlp_w1 = (const float*)d_in[10];
  const float* mlp_b1 = (const float*)d_in[11];
  const float* mlp_w2 = (const float*)d_in[12];
  const float* mlp_b2 = (const float*)d_in[13];
  const float* lnf_g  = (const float*)d_in[14];
  const float* lnf_b  = (const float*)d_in[15];
  const float* rw1    = (const float*)d_in[16];
  const float* rb1    = (const float*)d_in[17];
  const float* rw2    = (const float*)d_in[18];
  const float* rb2    = (const float*)d_in[19];
  const float* hw1    = (const float*)d_in[20];
  const float* hb1    = (const float*)d_in[21];
  const float* hw2    = (const float*)d_in[22];
  const float* hb2    = (const float*)d_in[23];
  float* out = (float*)d_out;

  char* base = (char*)d_ws; size_t off = 0;
  auto alloc = [&](size_t bytes) -> void* { void* p = base + off; off = (off + bytes + 255) & ~(size_t)255; return p; };

  u16* WQ   = (u16*)alloc((size_t)8 * 1536 * 512 * 2);
  u16* WAO  = (u16*)alloc((size_t)8 * 512 * 512 * 2);
  u16* W1t  = (u16*)alloc((size_t)8 * 512 * 512 * 2);
  u16* W2t  = (u16*)alloc((size_t)8 * 512 * 512 * 2);
  u16* WP   = (u16*)alloc((size_t)512 * 2048 * 2);
  u16* HF   = (u16*)alloc((size_t)ROWS * 512 * 2);
  u16* HH   = (u16*)alloc((size_t)4 * ROWS * 512 * 2);
  u16* YB   = (u16*)alloc((size_t)4 * ROWS * 512 * 2);
  u16* QKVb = (u16*)alloc((size_t)4 * ROWS * 1536 * 2);
  float* WEXP = (float*)alloc(64 * 4);
  int* PAIRS  = (int*)alloc(32 * 4);
  float* LAT  = (float*)alloc(4 * 16 * 512 * 4);
  float* BAGP = (float*)alloc((size_t)8 * 16 * 512 * 4);
  float* HIDP = (float*)alloc((size_t)16 * 8 * 256 * 4);
  float* PART = (float*)alloc((size_t)32 * 8 * 512 * 4);
  float* HIDP2 = (float*)alloc((size_t)16 * 4 * 128 * 4);
  u16* Y2B = QKVb;
  u16* TB  = QKVb + (size_t)4 * ROWS * 512;
  u16* OB  = YB;
  u16* Xf  = QKVb;  // dead until first qkv GEMM; proj consumes it before that

  castAll<<<dim3(16, 48, 32), 256, 0, stream>>>(qkv_w, ao_w, mlp_w1, mlp_w2, WQ, WAO, W1t, W2t);
  castTp<<<dim3(64, 16), 256, 0, stream>>>(proj_w, WP);
  xcast<<<8192, 256, 0, stream>>>(x, Xf);

  gemm_proj<<<dim3(128, 4), 256, 0, stream>>>(Xf, WP, proj_b, HF);
  bag_partial<<<dim3(16, 8), 512, 0, stream>>>(HF, BAGP);
  router_mm<<<dim3(8, 16), 256, 0, stream>>>(BAGP, rw1, HIDP);
  router_fin<<<16, 256, 0, stream>>>(HIDP, rb1, rw2, rb2, out + 8192 + 160, WEXP, PAIRS);

  for (int l = 0; l < 2; l++){
    if (l == 0)
      ln_rows<<<4096, 256, 0, stream>>>(HF, 0L, ln1_g, ln1_b, DEP * 512, YB, PAIRS);
    else
      ln_rows<<<4096, 256, 0, stream>>>(HH, ROWS * 512, ln1_g + 512, ln1_b + 512, DEP * 512, YB, PAIRS);
    gemm_bt<0, 128><<<dim3(128, 12), 256, 0, stream>>>(YB, 512, ROWS * 512, WQ + (long)l * 1536 * 512, (long)DEP * 1536 * 512,
                                                       nullptr, 0, QKVb, ROWS * 1536, 1536, PAIRS, nullptr);
    attn<<<1024, 256, 0, stream>>>(QKVb, OB, PAIRS);
    if (l == 0)
      gemm_bt<3, 64><<<dim3(256, 4), 256, 0, stream>>>(OB, 512, ROWS * 512, WAO, (long)DEP * 512 * 512,
                                                       ao_b, DEP * 512, HH, ROWS * 512, 512, PAIRS, HF);
    else
      gemm_bt<2, 64><<<dim3(256, 4), 256, 0, stream>>>(OB, 512, ROWS * 512, WAO + (long)512 * 512, (long)DEP * 512 * 512,
                                                       ao_b + 512, DEP * 512, HH, ROWS * 512, 512, PAIRS, nullptr);
    ln_rows<<<4096, 256, 0, stream>>>(HH, ROWS * 512, ln2_g + l * 512, ln2_b + l * 512, DEP * 512, Y2B, PAIRS);
    gemm_bt<1, 64><<<dim3(256, 4), 256, 0, stream>>>(Y2B, 512, ROWS * 512, W1t + (long)l * 512 * 512, (long)DEP * 512 * 512,
                                                     mlp_b1 + l * 512, DEP * 512, TB, ROWS * 512, 512, PAIRS, nullptr);
    gemm_bt<2, 64><<<dim3(256, 4), 256, 0, stream>>>(TB, 512, ROWS * 512, W2t + (long)l * 512 * 512, (long)DEP * 512 * 512,
                                                     mlp_b2 + l * 512, DEP * 512, HH, ROWS * 512, 512, PAIRS, nullptr);
  }

  lnf_partial<<<dim3(32, 8), 512, 0, stream>>>(HH, lnf_g, lnf_b, PART, PAIRS);
  lnf_fin<<<32, 512, 0, stream>>>(PART, LAT, PAIRS);
  head_l1<<<dim3(16, 4), 128, 0, stream>>>(LAT, WEXP, hw1, out, HIDP2);
  head_fin<<<16, 128, 0, stream>>>(HIDP2, hb1, hw2, hb2, out);
}